// Round 26
// baseline (127.326 us; speedup 1.0000x reference)
//
#include <hip/hip_runtime.h>
#include <hip/hip_cooperative_groups.h>

#define TPB 1024
#define GRID 256   // coop capacity on this stack is <=256 blocks (r2/r7). Never exceed.

// r25 post-mortem: 4 protocol variants flat at ~118 +/- 5. Last block-wide
// rendezvous = barrier1 (bias-ready). r26: barrier1 -> LDS fold-counter.
// Ordering proof: fold(L+1) <= gcnt>=16(L+1) <= publishers(L) <= lcnt>=16(L+1)
// <= every wave's WAVE_DONE(L) <= its hi-finish(L) reads. So red[] single
// buffer is safe, bias parity-dbuf covers lo-conv stragglers, gv is
// folder-local (w14 gv(L+1) write ordered after w15 fold(L) via gcnt chain).
// Layer loop now has ZERO block-wide barriers.

typedef float f2 __attribute__((ext_vector_type(2)));
static __device__ __forceinline__ f2 spl(float s) { f2 r; r.x = s; r.y = s; return r; }

__global__ void risnet_kernel(
    const float* __restrict__ channel,
    const float* __restrict__ We1, const float* __restrict__ be1,
    const float* __restrict__ We,  const float* __restrict__ be,
    const float* __restrict__ Wo1, const float* __restrict__ bo1,
    const float* __restrict__ Wo,  const float* __restrict__ bo,
    const float* __restrict__ W8,  const float* __restrict__ b8,
    float* __restrict__ out, float* __restrict__ part, int* __restrict__ gcnt)
{
  const int tid   = threadIdx.x;
  const int lane  = tid & 63;
  const int wv    = tid >> 6;                 // 0..15
  const int p     = tid & 1;                  // user-half: owns users 2p, 2p+1
  const int B     = blockIdx.x;
  const int b     = (B & 7) * 8 + ((B >> 3) & 7);  // same B%8 (XCD) per b-group (perf)
  const int chunk = B >> 6;                   // 0..3
  const int n     = (chunk << 9) | (tid >> 1);// 0..2047

  __shared__ __align__(16) float biasE[2][16][4];  // [L&1][h][u] parity dbuf
  __shared__ __align__(16) float biasO[2][16][4];
  __shared__ float red[64][64];                 // [row=(wv<<2)|(lane>>4)][conv*32+j*4+u]
  __shared__ float gv[64];                      // per-b mean deltas (w14/w15 write same)
  __shared__ float fin;
  __shared__ int   lcnt;                        // cumulative per-wave epoch count
  __shared__ int   bdone;                       // cumulative fold count (2 per layer)

  if (tid == 0) { lcnt = 0; bdone = 0; }

  // per-thread channel slice, packed over the user pair: ch2[f] = {u=2p, u=2p+1}
  f2 ch2[4];
#pragma unroll
  for (int f = 0; f < 4; ++f) {
    ch2[f].x = channel[((b*4 + 2*p + 0)*4 + f)*2048 + n];
    ch2[f].y = channel[((b*4 + 2*p + 1)*4 + f)*2048 + n];
  }
  __syncthreads();   // lcnt/bdone init visible before use

  f2 el2[8], ol2[8];
  float cum0 = 0.f, cum1 = 0.f;   // w14/w15: cumulative part-row values per parity
  int   pubt = 16;                // publisher waves: lcnt target per epoch

#define BFLY3(a0, a1) { \
  a0 += __shfl_xor(a0, 2, 64);  a1 += __shfl_xor(a1, 2, 64);  \
  a0 += __shfl_xor(a0, 4, 64);  a1 += __shfl_xor(a1, 4, 64);  \
  a0 += __shfl_xor(a0, 8, 64);  a1 += __shfl_xor(a1, 8, 64); }

#define RED_W(base_col, a0, a1) \
  if ((lane & 15) < 2) { \
    red[(wv<<2)|(lane>>4)][(base_col) + 2*(lane&1) + 0] = a0; \
    red[(wv<<2)|(lane>>4)][(base_col) + 2*(lane&1) + 1] = a1; }

  // this wave's red[] rows for the current epoch are complete
#define WAVE_DONE() { \
  asm volatile("s_waitcnt lgkmcnt(0)" ::: "memory"); \
  if (lane == 0) \
    __hip_atomic_fetch_add(&lcnt, 1, __ATOMIC_RELAXED, __HIP_MEMORY_SCOPE_WORKGROUP); }

  // waves 0..3: poll LDS counter to epoch target, sum OWN 16 rows, atomicAdd
  // into the CUMULATIVE parity row, drain, bump group counter.
#define PUBLISH_W03(par) \
  if (wv < 4) { \
    for (;;) { \
      int c = __hip_atomic_load(&lcnt, __ATOMIC_RELAXED, __HIP_MEMORY_SCOPE_WORKGROUP); \
      if (c >= pubt) break; \
      __builtin_amdgcn_s_sleep(0); \
    } \
    asm volatile("" ::: "memory"); \
    const int r0 = wv * 16; \
    float s0 = 0.f, s1 = 0.f, s2 = 0.f, s3 = 0.f; \
    _Pragma("unroll") for (int r = 0; r < 16; r += 4) { \
      s0 += red[r0+r+0][lane]; s1 += red[r0+r+1][lane]; \
      s2 += red[r0+r+2][lane]; s3 += red[r0+r+3][lane]; \
    } \
    unsafeAtomicAdd(&part[((par)*64 + b)*64 + lane], (s0+s1)+(s2+s3)); \
    asm volatile("s_waitcnt vmcnt(0)" ::: "memory"); \
    if (lane == 0) \
      __hip_atomic_fetch_add(&gcnt[b], 1, __ATOMIC_RELAXED, __HIP_MEMORY_SCOPE_AGENT); \
  } \
  pubt += 16;

  // single-address relaxed spin on the group counter
#define SPIN_CNT(tgt) { \
  for (;;) { \
    int c = __hip_atomic_load(&gcnt[b], __ATOMIC_RELAXED, __HIP_MEMORY_SCOPE_AGENT); \
    if (c >= (tgt)) break; \
    __builtin_amdgcn_s_sleep(1); \
  } \
  asm volatile("" ::: "memory"); }

  // spin on LDS fold counter (replaces barrier1)
#define SPIN_FOLD(tgt) { \
  for (;;) { \
    int c = __hip_atomic_load(&bdone, __ATOMIC_RELAXED, __HIP_MEMORY_SCOPE_WORKGROUP); \
    if (c >= (tgt)) break; \
    __builtin_amdgcn_s_sleep(0); \
  } \
  asm volatile("" ::: "memory"); }

  // packed 20-col dot product (ch 0..3, el 4..11, ol 20..27), BINIT = bias or 0
#define DOT20B(ACC, W0, W1, W2, W5, W6, BINIT) { \
  f2 v = (BINIT); \
  v = spl(W0.x)*ch2[0] + v; v = spl(W0.y)*ch2[1] + v; \
  v = spl(W0.z)*ch2[2] + v; v = spl(W0.w)*ch2[3] + v; \
  v = spl(W1.x)*el2[0] + v; v = spl(W1.y)*el2[1] + v; \
  v = spl(W1.z)*el2[2] + v; v = spl(W1.w)*el2[3] + v; \
  v = spl(W2.x)*el2[4] + v; v = spl(W2.y)*el2[5] + v; \
  v = spl(W2.z)*el2[6] + v; v = spl(W2.w)*el2[7] + v; \
  v = spl(W5.x)*ol2[0] + v; v = spl(W5.y)*ol2[1] + v; \
  v = spl(W5.z)*ol2[2] + v; v = spl(W5.w)*ol2[3] + v; \
  v = spl(W6.x)*ol2[4] + v; v = spl(W6.y)*ol2[5] + v; \
  v = spl(W6.z)*ol2[6] + v; v = spl(W6.w)*ol2[7] + v; \
  ACC = v; }

  // fold body: lane owns (u,h); folds ONE conv's bias from gv (in LDS),
  // then drains LDS writes and bumps the fold counter.
#define FOLD_ONE(W, bvec, dst) { \
  const int u = lane & 3; \
  const int h = lane >> 2; \
  float bias = (bvec)[(L-1)*16 + h]; \
  _Pragma("unroll") for (int j = 0; j < 8; ++j) { \
    const float eg = gv[j*4 + u]; \
    const float so = gv[32+j*4+0] + gv[32+j*4+1] + gv[32+j*4+2] + gv[32+j*4+3]; \
    const float og = (so - gv[32 + j*4 + u]) * (1.f/3.f); \
    bias += (W)[h*36 + 12 + j] * eg + (W)[h*36 + 28 + j] * og; \
  } \
  (dst)[h][u] = bias; \
  asm volatile("s_waitcnt lgkmcnt(0)" ::: "memory"); \
  if (lane == 0) \
    __hip_atomic_fetch_add(&bdone, 1, __ATOMIC_RELAXED, __HIP_MEMORY_SCOPE_WORKGROUP); }

  // ---------------- layer 0 (Cin = 4, feats = ch) ----------------
  {
    f2 opl2[8];
#pragma unroll
    for (int h = 0; h < 16; ++h) {
      const float4 w = *(const float4*)(We1 + h*4);
      f2 a = spl(be1[h]);
      a = spl(w.x)*ch2[0] + a; a = spl(w.y)*ch2[1] + a;
      a = spl(w.z)*ch2[2] + a; a = spl(w.w)*ch2[3] + a;
      a.x = fmaxf(a.x, 0.f); a.y = fmaxf(a.y, 0.f);
      if (h < 8) el2[h] = a;
      else { float a0 = a.x, a1 = a.y; BFLY3(a0, a1); RED_W((h-8)*4, a0, a1); }
    }
#pragma unroll
    for (int h = 0; h < 16; ++h) {
      const float4 w = *(const float4*)(Wo1 + h*4);
      f2 a = spl(bo1[h]);
      a = spl(w.x)*ch2[0] + a; a = spl(w.y)*ch2[1] + a;
      a = spl(w.z)*ch2[2] + a; a = spl(w.w)*ch2[3] + a;
      a.x = fmaxf(a.x, 0.f); a.y = fmaxf(a.y, 0.f);
      if (h < 8) opl2[h] = a;
      else { float a0 = a.x, a1 = a.y; BFLY3(a0, a1); RED_W(32 + (h-8)*4, a0, a1); }
    }
    WAVE_DONE()
    PUBLISH_W03(0)
#pragma unroll
    for (int j = 0; j < 8; ++j) {
      const float s2 = opl2[j].x + opl2[j].y;
      const float s4 = s2 + __shfl_xor(s2, 1, 64);
      ol2[j] = (spl(s4) - opl2[j]) * spl(1.f/3.f);
    }
  }

  // ---------------- layers 1..6 (Cin = 36) ----------------
  for (int L = 1; L < 7; ++L) {
    const float* __restrict__ wEl = We + (L-1)*576;   // wave-uniform -> s_loads
    const float* __restrict__ wOl = Wo + (L-1)*576;
    const int pr = (L-1) & 1;      // parity row holding stats(L-1) cumulative
    const int pw = L & 1;          // parity row this layer publishes into
    const int bb = L & 1;          // bias parity buffer

    // --- phase 1: HI accumulators for BOTH convs, no bias (32 VGPR) ---
    f2 accHiE[8], accHiO[8];
#pragma unroll
    for (int h = 8; h < 16; ++h) {
      const float4* wr = (const float4*)(wEl + h*36);
      const float4 w0 = wr[0], w1 = wr[1], w2 = wr[2], w5 = wr[5], w6 = wr[6];
      DOT20B(accHiE[h-8], w0, w1, w2, w5, w6, spl(0.f))
    }
#pragma unroll
    for (int h = 8; h < 16; ++h) {
      const float4* wr = (const float4*)(wOl + h*36);
      const float4 w0 = wr[0], w1 = wr[1], w2 = wr[2], w5 = wr[5], w6 = wr[6];
      DOT20B(accHiO[h-8], w0, w1, w2, w5, w6, spl(0.f))
    }

    // --- w15/w14: spin, read ONE cumulative row, delta, fold E / fold O ---
    if (wv >= 14) {
      SPIN_CNT(16*L)
      float R = __hip_atomic_load(&part[(pr*64 + b)*64 + lane],
                                  __ATOMIC_RELAXED, __HIP_MEMORY_SCOPE_AGENT);
      float prev = pr ? cum1 : cum0;
      float d = R - prev;
      if (pr) cum1 = R; else cum0 = R;
      gv[lane] = d * (1.f/2048.f);   // folder-local: each folder writes all 64
      if (wv == 15) { FOLD_ONE(wEl, be, biasE[bb]) }
      else          { FOLD_ONE(wOl, bo, biasO[bb]) }
    }
    // NO block barrier: waves proceed as soon as both folds are visible
    SPIN_FOLD(2*L)

    // --- hi finish: bias + relu + bfly only (NO conv on the publish path) ---
#pragma unroll
    for (int h = 8; h < 16; ++h) {
      f2 a = accHiE[h-8] + *(const f2*)&biasE[bb][h][2*p];
      float a0 = fmaxf(a.x, 0.f), a1 = fmaxf(a.y, 0.f);
      BFLY3(a0, a1); RED_W((h-8)*4, a0, a1);
    }
#pragma unroll
    for (int h = 8; h < 16; ++h) {
      f2 a = accHiO[h-8] + *(const f2*)&biasO[bb][h][2*p];
      float a0 = fmaxf(a.x, 0.f), a1 = fmaxf(a.y, 0.f);
      BFLY3(a0, a1); RED_W(32 + (h-8)*4, a0, a1);
    }
    WAVE_DONE()
    PUBLISH_W03(pw)   // waves 0-3 publish; others fall through to lo halves

    // --- lo convs in the publish shadow (bias-init, biases known) ---
    f2 eln2[8];
#pragma unroll
    for (int h = 0; h < 8; ++h) {
      const float4* wr = (const float4*)(wEl + h*36);
      const float4 w0 = wr[0], w1 = wr[1], w2 = wr[2], w5 = wr[5], w6 = wr[6];
      f2 a;
      DOT20B(a, w0, w1, w2, w5, w6, *(const f2*)&biasE[bb][h][2*p])
      a.x = fmaxf(a.x, 0.f); a.y = fmaxf(a.y, 0.f);
      eln2[h] = a;
    }
    f2 opl2[8];
#pragma unroll
    for (int h = 0; h < 8; ++h) {
      const float4* wr = (const float4*)(wOl + h*36);
      const float4 w0 = wr[0], w1 = wr[1], w2 = wr[2], w5 = wr[5], w6 = wr[6];
      f2 a;
      DOT20B(a, w0, w1, w2, w5, w6, *(const f2*)&biasO[bb][h][2*p])
      a.x = fmaxf(a.x, 0.f); a.y = fmaxf(a.y, 0.f);
      opl2[h] = a;
    }
#pragma unroll
    for (int j = 0; j < 8; ++j) {
      const float s2 = opl2[j].x + opl2[j].y;
      const float s4 = s2 + __shfl_xor(s2, 1, 64);
      ol2[j] = (spl(s4) - opl2[j]) * spl(1.f/3.f);
      el2[j] = eln2[j];
    }
  }

  // ---------------- final 1x1 conv + mean over users ----------------
  if (wv == 15) {   // layer 6 published parity 0; 7 epochs x 16 bumps = 112
    SPIN_CNT(112)
    float R = __hip_atomic_load(&part[(0*64 + b)*64 + lane],
                                __ATOMIC_RELAXED, __HIP_MEMORY_SCOPE_AGENT);
    gv[lane] = (R - cum0) * (1.f/2048.f);
    if (lane == 0) {
      float sf = b8[0];
#pragma unroll
      for (int j = 0; j < 8; ++j) {
        const float so = gv[32+j*4+0] + gv[32+j*4+1] + gv[32+j*4+2] + gv[32+j*4+3];
#pragma unroll
        for (int u = 0; u < 4; ++u) {
          const float eg = gv[j*4 + u];
          const float og = (so - gv[32 + j*4 + u]) * (1.f/3.f);
          sf += 0.25f * (W8[12 + j] * eg + W8[28 + j] * og);
        }
      }
      fin = sf;
    }
  }
  __syncthreads();
  f2 v = spl(0.f);
#pragma unroll
  for (int c = 0; c < 4; ++c) v = spl(W8[c]) * ch2[c] + v;
#pragma unroll
  for (int j = 0; j < 8; ++j) {
    v = spl(W8[4 + j]) * el2[j] + v;
    v = spl(W8[20 + j]) * ol2[j] + v;
  }
  float t = v.x + v.y;
  t += __shfl_xor(t, 1, 64);   // sum over all 4 users
  if (p == 0)
    out[b*2048 + n] = (fin + 0.25f * t) * 3.14159265358979f;
}

extern "C" void kernel_launch(void* const* d_in, const int* in_sizes, int n_in,
                              void* d_out, int out_size, void* d_ws, size_t ws_size,
                              hipStream_t stream) {
  const float* channel = (const float*)d_in[0];
  const float* We1 = (const float*)d_in[1];
  const float* be1 = (const float*)d_in[2];
  const float* We  = (const float*)d_in[3];
  const float* be  = (const float*)d_in[4];
  const float* Wo1 = (const float*)d_in[5];
  const float* bo1 = (const float*)d_in[6];
  const float* Wo  = (const float*)d_in[7];
  const float* bo  = (const float*)d_in[8];
  const float* W8  = (const float*)d_in[9];
  const float* b8  = (const float*)d_in[10];
  float* out  = (float*)d_out;
  float* part = (float*)d_ws;                       // 2*64*64 floats = 32768 B (cumulative)
  int*   gcnt = (int*)((char*)d_ws + 32768);        // 64 ints

  // stream-ordered zeroing of cumulative rows + counters (graph-capturable)
  hipMemsetAsync(d_ws, 0, 32768 + 64 * sizeof(int), stream);

  void* args[] = { (void*)&channel, (void*)&We1, (void*)&be1, (void*)&We, (void*)&be,
                   (void*)&Wo1, (void*)&bo1, (void*)&Wo, (void*)&bo,
                   (void*)&W8, (void*)&b8, (void*)&out, (void*)&part, (void*)&gcnt };
  hipLaunchCooperativeKernel((void*)risnet_kernel, dim3(GRID), dim3(TPB), args, 0, stream);
}

// Round 27
// 115.125 us; speedup vs baseline: 1.1060x; 1.1060x over previous
//
#include <hip/hip_runtime.h>
#include <hip/hip_cooperative_groups.h>

#define TPB 1024
#define GRID 256   // coop capacity on this stack is <=256 blocks (r2/r7). Never exceed.

// FINAL (r27 = r23 verbatim, best measured: 117.77us harness / ~112 steady).
// Session summary: 496 -> 119 us (4.2x). Remaining profile: busy ~57us (conv
// floor ~25us + protocol/spin instructions), stall ~60us = 7-deep
// algorithmically-serial cross-block chain (stats -> coherence-point RT ->
// fold -> bias -> next stats), ~2-3us/hop un-hidable. Five protocol variants
// (r22-r26) all flat 118-127 -> structural plateau for this decomposition.

typedef float f2 __attribute__((ext_vector_type(2)));
static __device__ __forceinline__ f2 spl(float s) { f2 r; r.x = s; r.y = s; return r; }

__global__ void risnet_kernel(
    const float* __restrict__ channel,
    const float* __restrict__ We1, const float* __restrict__ be1,
    const float* __restrict__ We,  const float* __restrict__ be,
    const float* __restrict__ Wo1, const float* __restrict__ bo1,
    const float* __restrict__ Wo,  const float* __restrict__ bo,
    const float* __restrict__ W8,  const float* __restrict__ b8,
    float* __restrict__ out, float* __restrict__ part, int* __restrict__ gcnt)
{
  const int tid   = threadIdx.x;
  const int lane  = tid & 63;
  const int wv    = tid >> 6;                 // 0..15
  const int p     = tid & 1;                  // user-half: owns users 2p, 2p+1
  const int B     = blockIdx.x;
  const int b     = (B & 7) * 8 + ((B >> 3) & 7);  // same B%8 (XCD) per b-group (perf)
  const int chunk = B >> 6;                   // 0..3
  const int n     = (chunk << 9) | (tid >> 1);// 0..2047

  __shared__ __align__(16) float biasE[2][16][4];  // [L&1][h][u] parity dbuf
  __shared__ __align__(16) float biasO[2][16][4];
  __shared__ float red[64][64];                 // [row=(wv<<2)|(lane>>4)][conv*32+j*4+u]
  __shared__ float gv[64];                      // per-b mean deltas (wave15 only)
  __shared__ float fin;
  __shared__ int   lcnt;                        // cumulative per-wave publish count

  if (tid == 0) lcnt = 0;

  // per-thread channel slice, packed over the user pair: ch2[f] = {u=2p, u=2p+1}
  f2 ch2[4];
#pragma unroll
  for (int f = 0; f < 4; ++f) {
    ch2[f].x = channel[((b*4 + 2*p + 0)*4 + f)*2048 + n];
    ch2[f].y = channel[((b*4 + 2*p + 1)*4 + f)*2048 + n];
  }
  __syncthreads();   // lcnt init visible before any WAVE_DONE

  f2 el2[8], ol2[8];
  float cum0 = 0.f, cum1 = 0.f;   // wave15: cumulative part-row values per parity
  int   pubt = 16;                // wave0: LDS-counter target for next publish

#define BFLY3(a0, a1) { \
  a0 += __shfl_xor(a0, 2, 64);  a1 += __shfl_xor(a1, 2, 64);  \
  a0 += __shfl_xor(a0, 4, 64);  a1 += __shfl_xor(a1, 4, 64);  \
  a0 += __shfl_xor(a0, 8, 64);  a1 += __shfl_xor(a1, 8, 64); }

#define RED_W(base_col, a0, a1) \
  if ((lane & 15) < 2) { \
    red[(wv<<2)|(lane>>4)][(base_col) + 2*(lane&1) + 0] = a0; \
    red[(wv<<2)|(lane>>4)][(base_col) + 2*(lane&1) + 1] = a1; }

  // this wave's red[] rows for the current epoch are complete
#define WAVE_DONE() { \
  asm volatile("s_waitcnt lgkmcnt(0)" ::: "memory"); \
  if (lane == 0) \
    __hip_atomic_fetch_add(&lcnt, 1, __ATOMIC_RELAXED, __HIP_MEMORY_SCOPE_WORKGROUP); }

  // wave0: poll LDS counter to epoch target, column-sum red, atomicAdd into
  // the CUMULATIVE parity row, drain, bump group counter. No block barrier.
#define PUBLISH_W0(par) \
  if (wv == 0) { \
    for (;;) { \
      int c = __hip_atomic_load(&lcnt, __ATOMIC_RELAXED, __HIP_MEMORY_SCOPE_WORKGROUP); \
      if (c >= pubt) break; \
      __builtin_amdgcn_s_sleep(0); \
    } \
    asm volatile("" ::: "memory"); \
    float s0 = 0.f, s1 = 0.f, s2 = 0.f, s3 = 0.f; \
    _Pragma("unroll") for (int r = 0; r < 64; r += 4) { \
      s0 += red[r+0][lane]; s1 += red[r+1][lane]; \
      s2 += red[r+2][lane]; s3 += red[r+3][lane]; \
    } \
    unsafeAtomicAdd(&part[((par)*64 + b)*64 + lane], (s0+s1)+(s2+s3)); \
    asm volatile("s_waitcnt vmcnt(0)" ::: "memory"); \
    if (lane == 0) \
      __hip_atomic_fetch_add(&gcnt[b], 1, __ATOMIC_RELAXED, __HIP_MEMORY_SCOPE_AGENT); \
  } \
  pubt += 16;

  // single-address relaxed spin on the group counter
#define SPIN_CNT(tgt) { \
  for (;;) { \
    int c = __hip_atomic_load(&gcnt[b], __ATOMIC_RELAXED, __HIP_MEMORY_SCOPE_AGENT); \
    if (c >= (tgt)) break; \
    __builtin_amdgcn_s_sleep(1); \
  } \
  asm volatile("" ::: "memory"); }

  // packed 20-col dot product (ch 0..3, el 4..11, ol 20..27), BINIT = bias or 0
#define DOT20B(ACC, W0, W1, W2, W5, W6, BINIT) { \
  f2 v = (BINIT); \
  v = spl(W0.x)*ch2[0] + v; v = spl(W0.y)*ch2[1] + v; \
  v = spl(W0.z)*ch2[2] + v; v = spl(W0.w)*ch2[3] + v; \
  v = spl(W1.x)*el2[0] + v; v = spl(W1.y)*el2[1] + v; \
  v = spl(W1.z)*el2[2] + v; v = spl(W1.w)*el2[3] + v; \
  v = spl(W2.x)*el2[4] + v; v = spl(W2.y)*el2[5] + v; \
  v = spl(W2.z)*el2[6] + v; v = spl(W2.w)*el2[7] + v; \
  v = spl(W5.x)*ol2[0] + v; v = spl(W5.y)*ol2[1] + v; \
  v = spl(W5.z)*ol2[2] + v; v = spl(W5.w)*ol2[3] + v; \
  v = spl(W6.x)*ol2[4] + v; v = spl(W6.y)*ol2[5] + v; \
  v = spl(W6.z)*ol2[6] + v; v = spl(W6.w)*ol2[7] + v; \
  ACC = v; }

  // ---------------- layer 0 (Cin = 4, feats = ch) ----------------
  {
    f2 opl2[8];
#pragma unroll
    for (int h = 0; h < 16; ++h) {
      const float4 w = *(const float4*)(We1 + h*4);
      f2 a = spl(be1[h]);
      a = spl(w.x)*ch2[0] + a; a = spl(w.y)*ch2[1] + a;
      a = spl(w.z)*ch2[2] + a; a = spl(w.w)*ch2[3] + a;
      a.x = fmaxf(a.x, 0.f); a.y = fmaxf(a.y, 0.f);
      if (h < 8) el2[h] = a;
      else { float a0 = a.x, a1 = a.y; BFLY3(a0, a1); RED_W((h-8)*4, a0, a1); }
    }
#pragma unroll
    for (int h = 0; h < 16; ++h) {
      const float4 w = *(const float4*)(Wo1 + h*4);
      f2 a = spl(bo1[h]);
      a = spl(w.x)*ch2[0] + a; a = spl(w.y)*ch2[1] + a;
      a = spl(w.z)*ch2[2] + a; a = spl(w.w)*ch2[3] + a;
      a.x = fmaxf(a.x, 0.f); a.y = fmaxf(a.y, 0.f);
      if (h < 8) opl2[h] = a;
      else { float a0 = a.x, a1 = a.y; BFLY3(a0, a1); RED_W(32 + (h-8)*4, a0, a1); }
    }
    WAVE_DONE()
    PUBLISH_W0(0)
#pragma unroll
    for (int j = 0; j < 8; ++j) {
      const float s2 = opl2[j].x + opl2[j].y;
      const float s4 = s2 + __shfl_xor(s2, 1, 64);
      ol2[j] = (spl(s4) - opl2[j]) * spl(1.f/3.f);
    }
  }

  // ---------------- layers 1..6 (Cin = 36) ----------------
  for (int L = 1; L < 7; ++L) {
    const float* __restrict__ wEl = We + (L-1)*576;   // wave-uniform -> s_loads
    const float* __restrict__ wOl = Wo + (L-1)*576;
    const int pr = (L-1) & 1;      // parity row holding stats(L-1) cumulative
    const int pw = L & 1;          // parity row this layer publishes into
    const int bb = L & 1;          // bias parity buffer

    // --- phase 1: HI accumulators for BOTH convs, no bias (32 VGPR) ---
    f2 accHiE[8], accHiO[8];
#pragma unroll
    for (int h = 8; h < 16; ++h) {
      const float4* wr = (const float4*)(wEl + h*36);
      const float4 w0 = wr[0], w1 = wr[1], w2 = wr[2], w5 = wr[5], w6 = wr[6];
      DOT20B(accHiE[h-8], w0, w1, w2, w5, w6, spl(0.f))
    }
#pragma unroll
    for (int h = 8; h < 16; ++h) {
      const float4* wr = (const float4*)(wOl + h*36);
      const float4 w0 = wr[0], w1 = wr[1], w2 = wr[2], w5 = wr[5], w6 = wr[6];
      DOT20B(accHiO[h-8], w0, w1, w2, w5, w6, spl(0.f))
    }

    // --- wave15: spin on group counter, read ONE cumulative row, delta, fold ---
    if (wv == 15) {
      SPIN_CNT(4*L)
      float R = __hip_atomic_load(&part[(pr*64 + b)*64 + lane],
                                  __ATOMIC_RELAXED, __HIP_MEMORY_SCOPE_AGENT);
      float prev = pr ? cum1 : cum0;
      float d = R - prev;
      if (pr) cum1 = R; else cum0 = R;
      gv[lane] = d * (1.f/2048.f);
      // same-wave LDS RAW (r11-verified): lane owns (u,h), folds both convs
      const int u = lane & 3;
      const int h = lane >> 2;
      float bE = be[(L-1)*16 + h];
      float bO = bo[(L-1)*16 + h];
#pragma unroll
      for (int j = 0; j < 8; ++j) {
        const float eg = gv[j*4 + u];
        const float so = gv[32+j*4+0] + gv[32+j*4+1] + gv[32+j*4+2] + gv[32+j*4+3];
        const float og = (so - gv[32 + j*4 + u]) * (1.f/3.f);
        bE += wEl[h*36 + 12 + j] * eg + wEl[h*36 + 28 + j] * og;
        bO += wOl[h*36 + 12 + j] * eg + wOl[h*36 + 28 + j] * og;
      }
      biasE[bb][h][u] = bE;
      biasO[bb][h][u] = bO;
    }
    __syncthreads();   // the ONLY block barrier this layer: biases ready

    // --- hi finish: bias + relu + bfly only (NO conv on the publish path) ---
#pragma unroll
    for (int h = 8; h < 16; ++h) {
      f2 a = accHiE[h-8] + *(const f2*)&biasE[bb][h][2*p];
      float a0 = fmaxf(a.x, 0.f), a1 = fmaxf(a.y, 0.f);
      BFLY3(a0, a1); RED_W((h-8)*4, a0, a1);
    }
#pragma unroll
    for (int h = 8; h < 16; ++h) {
      f2 a = accHiO[h-8] + *(const f2*)&biasO[bb][h][2*p];
      float a0 = fmaxf(a.x, 0.f), a1 = fmaxf(a.y, 0.f);
      BFLY3(a0, a1); RED_W(32 + (h-8)*4, a0, a1);
    }
    WAVE_DONE()
    PUBLISH_W0(pw)   // wave0 publishes; other waves fall through to lo halves

    // --- lo convs in the publish shadow (bias-init, biases known) ---
    f2 eln2[8];
#pragma unroll
    for (int h = 0; h < 8; ++h) {
      const float4* wr = (const float4*)(wEl + h*36);
      const float4 w0 = wr[0], w1 = wr[1], w2 = wr[2], w5 = wr[5], w6 = wr[6];
      f2 a;
      DOT20B(a, w0, w1, w2, w5, w6, *(const f2*)&biasE[bb][h][2*p])
      a.x = fmaxf(a.x, 0.f); a.y = fmaxf(a.y, 0.f);
      eln2[h] = a;
    }
    f2 opl2[8];
#pragma unroll
    for (int h = 0; h < 8; ++h) {
      const float4* wr = (const float4*)(wOl + h*36);
      const float4 w0 = wr[0], w1 = wr[1], w2 = wr[2], w5 = wr[5], w6 = wr[6];
      f2 a;
      DOT20B(a, w0, w1, w2, w5, w6, *(const f2*)&biasO[bb][h][2*p])
      a.x = fmaxf(a.x, 0.f); a.y = fmaxf(a.y, 0.f);
      opl2[h] = a;
    }
#pragma unroll
    for (int j = 0; j < 8; ++j) {
      const float s2 = opl2[j].x + opl2[j].y;
      const float s4 = s2 + __shfl_xor(s2, 1, 64);
      ol2[j] = (spl(s4) - opl2[j]) * spl(1.f/3.f);
      el2[j] = eln2[j];
    }
  }

  // ---------------- final 1x1 conv + mean over users ----------------
  if (wv == 15) {   // layer 6 published parity 0; 7 epochs x 4 bumps = 28
    SPIN_CNT(28)
    float R = __hip_atomic_load(&part[(0*64 + b)*64 + lane],
                                __ATOMIC_RELAXED, __HIP_MEMORY_SCOPE_AGENT);
    gv[lane] = (R - cum0) * (1.f/2048.f);
    if (lane == 0) {
      float sf = b8[0];
#pragma unroll
      for (int j = 0; j < 8; ++j) {
        const float so = gv[32+j*4+0] + gv[32+j*4+1] + gv[32+j*4+2] + gv[32+j*4+3];
#pragma unroll
        for (int u = 0; u < 4; ++u) {
          const float eg = gv[j*4 + u];
          const float og = (so - gv[32 + j*4 + u]) * (1.f/3.f);
          sf += 0.25f * (W8[12 + j] * eg + W8[28 + j] * og);
        }
      }
      fin = sf;
    }
  }
  __syncthreads();
  f2 v = spl(0.f);
#pragma unroll
  for (int c = 0; c < 4; ++c) v = spl(W8[c]) * ch2[c] + v;
#pragma unroll
  for (int j = 0; j < 8; ++j) {
    v = spl(W8[4 + j]) * el2[j] + v;
    v = spl(W8[20 + j]) * ol2[j] + v;
  }
  float t = v.x + v.y;
  t += __shfl_xor(t, 1, 64);   // sum over all 4 users
  if (p == 0)
    out[b*2048 + n] = (fin + 0.25f * t) * 3.14159265358979f;
}

extern "C" void kernel_launch(void* const* d_in, const int* in_sizes, int n_in,
                              void* d_out, int out_size, void* d_ws, size_t ws_size,
                              hipStream_t stream) {
  const float* channel = (const float*)d_in[0];
  const float* We1 = (const float*)d_in[1];
  const float* be1 = (const float*)d_in[2];
  const float* We  = (const float*)d_in[3];
  const float* be  = (const float*)d_in[4];
  const float* Wo1 = (const float*)d_in[5];
  const float* bo1 = (const float*)d_in[6];
  const float* Wo  = (const float*)d_in[7];
  const float* bo  = (const float*)d_in[8];
  const float* W8  = (const float*)d_in[9];
  const float* b8  = (const float*)d_in[10];
  float* out  = (float*)d_out;
  float* part = (float*)d_ws;                       // 2*64*64 floats = 32768 B (cumulative)
  int*   gcnt = (int*)((char*)d_ws + 32768);        // 64 ints

  // stream-ordered zeroing of cumulative rows + counters (graph-capturable)
  hipMemsetAsync(d_ws, 0, 32768 + 64 * sizeof(int), stream);

  void* args[] = { (void*)&channel, (void*)&We1, (void*)&be1, (void*)&We, (void*)&be,
                   (void*)&Wo1, (void*)&bo1, (void*)&Wo, (void*)&bo,
                   (void*)&W8, (void*)&b8, (void*)&out, (void*)&part, (void*)&gcnt };
  hipLaunchCooperativeKernel((void*)risnet_kernel, dim3(GRID), dim3(TPB), args, 0, stream);
}